// Round 1
// baseline (637.025 us; speedup 1.0000x reference)
//
#include <hip/hip_runtime.h>
#include <hip/hip_bf16.h>

#define NNODES 50000
#define NEDGES 800000
#define NEG_SLOPE 0.2f

// ---------------- CSR build ----------------

__global__ void count_deg(const int* __restrict__ dst, int* __restrict__ deg, int E) {
    int i = blockIdx.x * blockDim.x + threadIdx.x;
    if (i < E) atomicAdd(&deg[dst[i]], 1);
}

// single-block exclusive scan over N ints -> rowptr[0..N], also copies to cursor
__global__ void scan_kernel(const int* __restrict__ deg, int* __restrict__ rowptr,
                            int* __restrict__ cursor, int N) {
    __shared__ int buf[1024];
    __shared__ int scarry;
    int t = threadIdx.x;
    if (t == 0) scarry = 0;
    __syncthreads();
    for (int start = 0; start < N; start += 1024) {
        int i = start + t;
        int v = (i < N) ? deg[i] : 0;
        buf[t] = v;
        __syncthreads();
        for (int off = 1; off < 1024; off <<= 1) {
            int x = (t >= off) ? buf[t - off] : 0;
            __syncthreads();
            buf[t] += x;
            __syncthreads();
        }
        int incl = buf[t];
        int base = scarry;
        int total = buf[1023];
        __syncthreads();
        if (i < N) {
            int e = base + incl - v;
            rowptr[i] = e;
            cursor[i] = e;
        }
        if (t == 0) scarry = base + total;
        __syncthreads();
    }
    if (t == 0) rowptr[N] = scarry;
}

__global__ void scatter_edges(const int* __restrict__ src, const int* __restrict__ dst,
                              int* __restrict__ cursor, int* __restrict__ csrc, int E) {
    int i = blockIdx.x * blockDim.x + threadIdx.x;
    if (i < E) {
        int pos = atomicAdd(&cursor[dst[i]], 1);
        csrc[pos] = src[i];
    }
}

// ---------------- GEMM + attention logits ----------------
// feat[n][c] = sum_k X[n][k] * W[k][c];  el[n][h] = sum_d feat[n][h][d]*al[h][d]
// C = H*D total output cols. One 64-lane wave handles 64 cols; WPN = C/64 waves per node.
template <int K, int C, int D>
__global__ __launch_bounds__(256) void gemm_feat(
    const float* __restrict__ X, const float* __restrict__ W,
    const float* __restrict__ AL, const float* __restrict__ AR,
    float* __restrict__ feat, float* __restrict__ el, float* __restrict__ er, int N) {
    __shared__ float Wl[K * C];
    __shared__ float All[C], Arl[C];
    for (int i = threadIdx.x; i < K * C; i += 256) Wl[i] = W[i];
    for (int i = threadIdx.x; i < C; i += 256) { All[i] = AL[i]; Arl[i] = AR[i]; }
    __syncthreads();

    constexpr int WPN = C / 64;   // waves per node
    constexpr int NPB = 4 / WPN;  // nodes per block iteration (256 thr = 4 waves)
    constexpr int H = C / D;
    int wave = threadIdx.x >> 6;
    int lane = threadIdx.x & 63;
    int sub = wave % WPN;
    int nodeInBlk = wave / WPN;
    int c = sub * 64 + lane;

    for (int n = blockIdx.x * NPB + nodeInBlk; n < N; n += gridDim.x * NPB) {
        int nu = __builtin_amdgcn_readfirstlane(n);
        const float* xr = X + (size_t)nu * K;
        float acc = 0.f;
#pragma unroll
        for (int k = 0; k < K; k++) acc += xr[k] * Wl[k * C + c];
        feat[(size_t)nu * C + c] = acc;
        float vl = acc * All[c];
        float vr = acc * Arl[c];
#pragma unroll
        for (int m = 1; m < D; m <<= 1) {
            vl += __shfl_xor(vl, m, 64);
            vr += __shfl_xor(vr, m, 64);
        }
        if ((c % D) == 0) {
            int h = c / D;
            el[(size_t)nu * H + h] = vl;
            er[(size_t)nu * H + h] = vr;
        }
    }
}

// ---------------- Aggregation (edge softmax + weighted sum) ----------------
// D=32, H=2: one wave per node, lane = h*32+d. Output [N,64] with bias+ReLU.
template <bool RELU>
__global__ __launch_bounds__(256) void aggregate32(
    const int* __restrict__ rowptr, const int* __restrict__ csrc,
    const float* __restrict__ feat, const float* __restrict__ el,
    const float* __restrict__ er, const float* __restrict__ b,
    float* __restrict__ out, int N) {
    int wave = threadIdx.x >> 6;
    int lane = threadIdx.x & 63;
    int h = lane >> 5;
    float bl = b[lane];
    for (int n = blockIdx.x * 4 + wave; n < N; n += gridDim.x * 4) {
        int nu = __builtin_amdgcn_readfirstlane(n);
        int beg = __builtin_amdgcn_readfirstlane(rowptr[nu]);
        int end = __builtin_amdgcn_readfirstlane(rowptr[nu + 1]);
        float ern = er[nu * 2 + h];
        float s = 0.f, acc = 0.f;
        for (int i = beg; i < end; i++) {
            int src = __builtin_amdgcn_readfirstlane(csrc[i]);
            float t = el[src * 2 + h] + ern;
            t = t > 0.f ? t : NEG_SLOPE * t;
            float w = __expf(t);
            s += w;
            acc += w * feat[(size_t)src * 64 + lane];
        }
        float v = (s > 0.f) ? acc / s : 0.f;
        v += bl;
        if (RELU) v = fmaxf(v, 0.f);
        out[(size_t)nu * 64 + lane] = v;
    }
}

// D=64, H=2 (output layer): two waves per node (one per head); mean over heads
// via atomicAdd into pre-zeroed out. out[n][d] = 0.5 * sum_h (rst_h[d] + b[h*64+d])
__global__ __launch_bounds__(256) void aggregate64_mean(
    const int* __restrict__ rowptr, const int* __restrict__ csrc,
    const float* __restrict__ feat, const float* __restrict__ el,
    const float* __restrict__ er, const float* __restrict__ b,
    float* __restrict__ out, int N) {
    int wave = threadIdx.x >> 6;
    int lane = threadIdx.x & 63;
    int h = wave & 1;
    float bl = b[h * 64 + lane];
    for (int n = blockIdx.x * 2 + (wave >> 1); n < N; n += gridDim.x * 2) {
        int nu = __builtin_amdgcn_readfirstlane(n);
        int beg = __builtin_amdgcn_readfirstlane(rowptr[nu]);
        int end = __builtin_amdgcn_readfirstlane(rowptr[nu + 1]);
        float ern = er[nu * 2 + h];
        float s = 0.f, acc = 0.f;
        for (int i = beg; i < end; i++) {
            int src = __builtin_amdgcn_readfirstlane(csrc[i]);
            float t = el[src * 2 + h] + ern;
            t = t > 0.f ? t : NEG_SLOPE * t;
            float w = __expf(t);
            s += w;
            acc += w * feat[(size_t)src * 128 + h * 64 + lane];
        }
        float v = (s > 0.f) ? acc / s : 0.f;
        v = 0.5f * (v + bl);
        atomicAdd(&out[(size_t)nu * 64 + lane], v);
    }
}

// ---------------- launcher ----------------

extern "C" void kernel_launch(void* const* d_in, const int* in_sizes, int n_in,
                              void* d_out, int out_size, void* d_ws, size_t ws_size,
                              hipStream_t stream) {
    const float* x   = (const float*)d_in[0];
    const int*   src = (const int*)d_in[1];
    const int*   dst = (const int*)d_in[2];
    const float* W0  = (const float*)d_in[3];
    const float* al0 = (const float*)d_in[4];
    const float* ar0 = (const float*)d_in[5];
    const float* b0  = (const float*)d_in[6];
    const float* W1  = (const float*)d_in[7];
    const float* al1 = (const float*)d_in[8];
    const float* ar1 = (const float*)d_in[9];
    const float* b1  = (const float*)d_in[10];
    const float* W2  = (const float*)d_in[11];
    const float* al2 = (const float*)d_in[12];
    const float* ar2 = (const float*)d_in[13];
    const float* b2  = (const float*)d_in[14];
    float* out = (float*)d_out;

    const int N = NNODES;
    const int E = in_sizes[1];

    // workspace carve
    char* p = (char*)d_ws;
    auto alloc = [&](size_t bytes) {
        void* r = (void*)p;
        p += (bytes + 255) & ~(size_t)255;
        return r;
    };
    int*   deg    = (int*)alloc((size_t)N * 4);
    int*   rowptr = (int*)alloc((size_t)(N + 1) * 4);
    int*   cursor = (int*)alloc((size_t)N * 4);
    int*   csrc   = (int*)alloc((size_t)E * 4);
    float* feat   = (float*)alloc((size_t)N * 128 * 4);
    float* el     = (float*)alloc((size_t)N * 2 * 4);
    float* er     = (float*)alloc((size_t)N * 2 * 4);
    float* hbuf   = (float*)alloc((size_t)N * 64 * 4);

    // CSR build (graph is layer-invariant)
    hipMemsetAsync(deg, 0, (size_t)N * 4, stream);
    hipMemsetAsync(out, 0, (size_t)N * 64 * 4, stream);
    int eb = (E + 255) / 256;
    count_deg<<<eb, 256, 0, stream>>>(dst, deg, E);
    scan_kernel<<<1, 1024, 0, stream>>>(deg, rowptr, cursor, N);
    scatter_edges<<<eb, 256, 0, stream>>>(src, dst, cursor, csrc, E);

    int nb4 = (N + 3) / 4;  // 4 nodes per block (1 wave/node)
    int nb2 = (N + 1) / 2;  // 2 nodes per block (2 waves/node)

    // layer 0: IN=128 -> H2xD32
    gemm_feat<128, 64, 32><<<nb4, 256, 0, stream>>>(x, W0, al0, ar0, feat, el, er, N);
    aggregate32<true><<<nb4, 256, 0, stream>>>(rowptr, csrc, feat, el, er, b0, hbuf, N);

    // layer 1: 64 -> H2xD32
    gemm_feat<64, 64, 32><<<nb4, 256, 0, stream>>>(hbuf, W1, al1, ar1, feat, el, er, N);
    aggregate32<true><<<nb4, 256, 0, stream>>>(rowptr, csrc, feat, el, er, b1, hbuf, N);

    // layer 2: 64 -> H2xD64, mean over heads
    gemm_feat<64, 128, 64><<<nb2, 256, 0, stream>>>(hbuf, W2, al2, ar2, feat, el, er, N);
    aggregate64_mean<<<nb2, 256, 0, stream>>>(rowptr, csrc, feat, el, er, b2, out, N);
}

// Round 2
// 450.727 us; speedup vs baseline: 1.4133x; 1.4133x over previous
//
#include <hip/hip_runtime.h>
#include <hip/hip_bf16.h>
#include <hip/hip_fp16.h>

#define NNODES 50000
#define NEG_SLOPE 0.2f

__device__ __forceinline__ int rfl(int v) { return __builtin_amdgcn_readfirstlane(v); }

// ---------------- CSR build ----------------

__global__ void count_deg(const int* __restrict__ dst, int* __restrict__ deg, int E) {
    int i = blockIdx.x * blockDim.x + threadIdx.x;
    if (i < E) atomicAdd(&deg[dst[i]], 1);
}

// S1: per-block (256 elems) sums
__global__ void scan_partial(const int* __restrict__ deg, int* __restrict__ blocksum, int N) {
    int i = blockIdx.x * 256 + threadIdx.x;
    int v = (i < N) ? deg[i] : 0;
#pragma unroll
    for (int m = 1; m < 64; m <<= 1) v += __shfl_xor(v, m, 64);
    __shared__ int ws[4];
    if ((threadIdx.x & 63) == 0) ws[threadIdx.x >> 6] = v;
    __syncthreads();
    if (threadIdx.x == 0) blocksum[blockIdx.x] = ws[0] + ws[1] + ws[2] + ws[3];
}

// S2: exclusive-scan the (<=256) block sums in one block
__global__ void scan_blocksums(int* __restrict__ blocksum, int nb) {
    __shared__ int buf[256];
    int t = threadIdx.x;
    int v = (t < nb) ? blocksum[t] : 0;
    buf[t] = v;
    __syncthreads();
    for (int off = 1; off < 256; off <<= 1) {
        int x = (t >= off) ? buf[t - off] : 0;
        __syncthreads();
        buf[t] += x;
        __syncthreads();
    }
    if (t < nb) blocksum[t] = buf[t] - v;  // exclusive
}

// S3: in-block inclusive scan + block base -> exclusive rowptr & cursor
__global__ void scan_final(const int* __restrict__ deg, const int* __restrict__ blocksum,
                           int* __restrict__ rowptr, int* __restrict__ cursor, int N, int E) {
    int i = blockIdx.x * 256 + threadIdx.x;
    int lane = threadIdx.x & 63;
    int v = (i < N) ? deg[i] : 0;
    int x = v;
#pragma unroll
    for (int m = 1; m < 64; m <<= 1) {
        int y = __shfl_up(x, m, 64);
        if (lane >= m) x += y;
    }
    __shared__ int ws[4];
    if (lane == 63) ws[threadIdx.x >> 6] = x;
    __syncthreads();
    int w = threadIdx.x >> 6;
    int waveoff = 0;
#pragma unroll
    for (int k = 0; k < 4; k++) if (k < w) waveoff += ws[k];
    int excl = blocksum[blockIdx.x] + waveoff + x - v;
    if (i < N) { rowptr[i] = excl; cursor[i] = excl; }
    if (i == N - 1) rowptr[N] = E;
}

__global__ void scatter_edges(const int* __restrict__ src, const int* __restrict__ dst,
                              int* __restrict__ cursor, int* __restrict__ csrc, int E) {
    int i = blockIdx.x * blockDim.x + threadIdx.x;
    if (i < E) {
        int pos = atomicAdd(&cursor[dst[i]], 1);
        csrc[pos] = src[i];
    }
}

// ---------------- GEMM + attention logits ----------------
// Layers 0/1: C=64 (H=2 x D=32), one wave per node; lane = h*32+d.
template <int K>
__global__ __launch_bounds__(256) void gemm32(
    const float* __restrict__ X, const float* __restrict__ W,
    const float* __restrict__ AL, const float* __restrict__ AR,
    __half* __restrict__ feat16, float* __restrict__ el, float* __restrict__ er, int N) {
    __shared__ float Wl[K * 64];
    __shared__ float All[64], Arl[64];
    for (int i = threadIdx.x; i < K * 64; i += 256) Wl[i] = W[i];
    if (threadIdx.x < 64) { All[threadIdx.x] = AL[threadIdx.x]; Arl[threadIdx.x] = AR[threadIdx.x]; }
    __syncthreads();
    int wave = threadIdx.x >> 6, lane = threadIdx.x & 63;
    int n = rfl(blockIdx.x * 4 + wave);
    if (n >= N) return;
    const float* xr = X + (size_t)n * K;
    float acc = 0.f;
#pragma unroll
    for (int k = 0; k < K; k++) acc += xr[k] * Wl[k * 64 + lane];
    feat16[(size_t)n * 64 + lane] = __float2half(acc);
    float vl = acc * All[lane], vr = acc * Arl[lane];
#pragma unroll
    for (int m = 1; m < 32; m <<= 1) {
        vl += __shfl_xor(vl, m, 64);
        vr += __shfl_xor(vr, m, 64);
    }
    if ((lane & 31) == 0) {
        int h = lane >> 5;
        el[n * 2 + h] = vl;
        er[n * 2 + h] = vr;
    }
}

// Layer 2: C=128 (H=2 x D=64), one wave per node; lane = d, both heads in regs.
// feat stored interleaved as __half2 {h0,h1} per (n,d).
__global__ __launch_bounds__(256) void gemm64(
    const float* __restrict__ X, const float* __restrict__ W,
    const float* __restrict__ AL, const float* __restrict__ AR,
    __half2* __restrict__ feat2, float* __restrict__ el, float* __restrict__ er, int N) {
    __shared__ float Wl[64 * 128];  // 32 KB
    __shared__ float All[128], Arl[128];
    for (int i = threadIdx.x; i < 64 * 128; i += 256) Wl[i] = W[i];
    if (threadIdx.x < 128) { All[threadIdx.x] = AL[threadIdx.x]; Arl[threadIdx.x] = AR[threadIdx.x]; }
    __syncthreads();
    int wave = threadIdx.x >> 6, d = threadIdx.x & 63;
    int n = rfl(blockIdx.x * 4 + wave);
    if (n >= N) return;
    const float* xr = X + (size_t)n * 64;
    float a0 = 0.f, a1 = 0.f;
#pragma unroll
    for (int k = 0; k < 64; k++) {
        float xv = xr[k];
        a0 += xv * Wl[k * 128 + d];
        a1 += xv * Wl[k * 128 + 64 + d];
    }
    feat2[(size_t)n * 64 + d] = __floats2half2_rn(a0, a1);
    float l0 = a0 * All[d], r0 = a0 * Arl[d];
    float l1 = a1 * All[64 + d], r1 = a1 * Arl[64 + d];
#pragma unroll
    for (int m = 1; m < 64; m <<= 1) {
        l0 += __shfl_xor(l0, m, 64);
        r0 += __shfl_xor(r0, m, 64);
        l1 += __shfl_xor(l1, m, 64);
        r1 += __shfl_xor(r1, m, 64);
    }
    if (d == 0) {
        el[n * 2 + 0] = l0; el[n * 2 + 1] = l1;
        er[n * 2 + 0] = r0; er[n * 2 + 1] = r1;
    }
}

// ---------------- Aggregation ----------------
// Layers 0/1: one wave per node, lane = h*32+d. fp16 feat gather.
template <bool RELU>
__global__ __launch_bounds__(256) void aggregate32(
    const int* __restrict__ rowptr, const int* __restrict__ csrc,
    const __half* __restrict__ feat16, const float* __restrict__ el,
    const float* __restrict__ er, const float* __restrict__ b,
    float* __restrict__ out, int N) {
    int wave = threadIdx.x >> 6, lane = threadIdx.x & 63, h = lane >> 5;
    float bl = b[lane];
    int n = rfl(blockIdx.x * 4 + wave);
    if (n >= N) return;
    int beg = rfl(rowptr[n]), end = rfl(rowptr[n + 1]);
    float ern = er[n * 2 + h];
    float s = 0.f, acc = 0.f;
    for (int base = beg; base < end; base += 64) {
        int eidx = base + lane;
        int sv = (eidx < end) ? csrc[eidx] : 0;
        int cnt = min(64, end - base);
        int j = 0;
        for (; j + 1 < cnt; j += 2) {
            int s0 = __shfl(sv, j, 64);
            int s1 = __shfl(sv, j + 1, 64);
            float f0 = __half2float(feat16[(size_t)s0 * 64 + lane]);
            float f1 = __half2float(feat16[(size_t)s1 * 64 + lane]);
            float t0 = el[s0 * 2 + h] + ern; t0 = t0 > 0.f ? t0 : NEG_SLOPE * t0;
            float t1 = el[s1 * 2 + h] + ern; t1 = t1 > 0.f ? t1 : NEG_SLOPE * t1;
            float w0 = __expf(t0), w1 = __expf(t1);
            s += w0 + w1;
            acc += w0 * f0 + w1 * f1;
        }
        if (j < cnt) {
            int s0 = __shfl(sv, j, 64);
            float f0 = __half2float(feat16[(size_t)s0 * 64 + lane]);
            float t0 = el[s0 * 2 + h] + ern; t0 = t0 > 0.f ? t0 : NEG_SLOPE * t0;
            float w0 = __expf(t0);
            s += w0;
            acc += w0 * f0;
        }
    }
    float v = (s > 0.f) ? acc / s : 0.f;
    v += bl;
    if (RELU) v = fmaxf(v, 0.f);
    out[(size_t)n * 64 + lane] = v;
}

// Layer 2: one wave per node handles BOTH heads (half2 interleave), mean over heads.
__global__ __launch_bounds__(256) void aggregate64_mean(
    const int* __restrict__ rowptr, const int* __restrict__ csrc,
    const __half2* __restrict__ feat2, const float* __restrict__ el,
    const float* __restrict__ er, const float* __restrict__ b,
    float* __restrict__ out, int N) {
    int wave = threadIdx.x >> 6, lane = threadIdx.x & 63;
    int n = rfl(blockIdx.x * 4 + wave);
    if (n >= N) return;
    float b0 = b[lane], b1 = b[64 + lane];
    int beg = rfl(rowptr[n]), end = rfl(rowptr[n + 1]);
    float er0 = er[n * 2 + 0], er1 = er[n * 2 + 1];
    float s0 = 0.f, s1 = 0.f, a0 = 0.f, a1 = 0.f;
    for (int base = beg; base < end; base += 64) {
        int eidx = base + lane;
        int sv = (eidx < end) ? csrc[eidx] : 0;
        int cnt = min(64, end - base);
        for (int j = 0; j < cnt; j++) {
            int sj = __shfl(sv, j, 64);
            float2 ff = __half22float2(feat2[(size_t)sj * 64 + lane]);
            float t0 = el[sj * 2 + 0] + er0; t0 = t0 > 0.f ? t0 : NEG_SLOPE * t0;
            float t1 = el[sj * 2 + 1] + er1; t1 = t1 > 0.f ? t1 : NEG_SLOPE * t1;
            float w0 = __expf(t0), w1 = __expf(t1);
            s0 += w0; s1 += w1;
            a0 += w0 * ff.x; a1 += w1 * ff.y;
        }
    }
    float v0 = (s0 > 0.f) ? a0 / s0 : 0.f;
    float v1 = (s1 > 0.f) ? a1 / s1 : 0.f;
    out[(size_t)n * 64 + lane] = 0.5f * ((v0 + b0) + (v1 + b1));
}

// ---------------- launcher ----------------

extern "C" void kernel_launch(void* const* d_in, const int* in_sizes, int n_in,
                              void* d_out, int out_size, void* d_ws, size_t ws_size,
                              hipStream_t stream) {
    const float* x   = (const float*)d_in[0];
    const int*   src = (const int*)d_in[1];
    const int*   dst = (const int*)d_in[2];
    const float* W0  = (const float*)d_in[3];
    const float* al0 = (const float*)d_in[4];
    const float* ar0 = (const float*)d_in[5];
    const float* b0  = (const float*)d_in[6];
    const float* W1  = (const float*)d_in[7];
    const float* al1 = (const float*)d_in[8];
    const float* ar1 = (const float*)d_in[9];
    const float* b1  = (const float*)d_in[10];
    const float* W2  = (const float*)d_in[11];
    const float* al2 = (const float*)d_in[12];
    const float* ar2 = (const float*)d_in[13];
    const float* b2  = (const float*)d_in[14];
    float* out = (float*)d_out;

    const int N = NNODES;
    const int E = in_sizes[1];

    char* p = (char*)d_ws;
    auto alloc = [&](size_t bytes) {
        void* r = (void*)p;
        p += (bytes + 255) & ~(size_t)255;
        return r;
    };
    int*   deg      = (int*)alloc((size_t)N * 4);
    int*   rowptr   = (int*)alloc((size_t)(N + 1) * 4);
    int*   cursor   = (int*)alloc((size_t)N * 4);
    int*   blocksum = (int*)alloc(256 * 4);
    int*   csrc     = (int*)alloc((size_t)E * 4);
    float* el       = (float*)alloc((size_t)N * 2 * 4);
    float* er       = (float*)alloc((size_t)N * 2 * 4);
    void*  featbuf  = alloc((size_t)N * 64 * 4);   // half[N][64] or half2[N][64]
    float* hbuf     = (float*)alloc((size_t)N * 64 * 4);
    __half*  feat16 = (__half*)featbuf;
    __half2* feat2  = (__half2*)featbuf;

    // CSR build (graph is layer-invariant)
    hipMemsetAsync(deg, 0, (size_t)N * 4, stream);
    int eb = (E + 255) / 256;
    int nb256 = (N + 255) / 256;  // 196
    count_deg<<<eb, 256, 0, stream>>>(dst, deg, E);
    scan_partial<<<nb256, 256, 0, stream>>>(deg, blocksum, N);
    scan_blocksums<<<1, 256, 0, stream>>>(blocksum, nb256);
    scan_final<<<nb256, 256, 0, stream>>>(deg, blocksum, rowptr, cursor, N, E);
    scatter_edges<<<eb, 256, 0, stream>>>(src, dst, cursor, csrc, E);

    int nb4 = (N + 3) / 4;  // one wave per node, 4 nodes/block

    // layer 0: IN=128 -> H2xD32
    gemm32<128><<<nb4, 256, 0, stream>>>(x, W0, al0, ar0, feat16, el, er, N);
    aggregate32<true><<<nb4, 256, 0, stream>>>(rowptr, csrc, feat16, el, er, b0, hbuf, N);

    // layer 1: 64 -> H2xD32
    gemm32<64><<<nb4, 256, 0, stream>>>(hbuf, W1, al1, ar1, feat16, el, er, N);
    aggregate32<true><<<nb4, 256, 0, stream>>>(rowptr, csrc, feat16, el, er, b1, hbuf, N);

    // layer 2: 64 -> H2xD64, mean over heads (half2-interleaved feat)
    gemm64<<<nb4, 256, 0, stream>>>(hbuf, W2, al2, ar2, feat2, el, er, N);
    aggregate64_mean<<<nb4, 256, 0, stream>>>(rowptr, csrc, feat2, el, er, b2, out, N);
}

// Round 4
// 403.005 us; speedup vs baseline: 1.5807x; 1.1184x over previous
//
#include <hip/hip_runtime.h>
#include <hip/hip_bf16.h>
#include <hip/hip_fp16.h>

#define NNODES 50000
#define NEG_SLOPE 0.2f

__device__ __forceinline__ int rfl(int v) { return __builtin_amdgcn_readfirstlane(v); }

// ---------------- CSR build ----------------

__global__ void count_deg(const int* __restrict__ dst, int* __restrict__ deg, int E) {
    int i = blockIdx.x * blockDim.x + threadIdx.x;
    if (i < E) atomicAdd(&deg[dst[i]], 1);
}

__global__ void scan_partial(const int* __restrict__ deg, int* __restrict__ blocksum, int N) {
    int i = blockIdx.x * 256 + threadIdx.x;
    int v = (i < N) ? deg[i] : 0;
#pragma unroll
    for (int m = 1; m < 64; m <<= 1) v += __shfl_xor(v, m, 64);
    __shared__ int ws[4];
    if ((threadIdx.x & 63) == 0) ws[threadIdx.x >> 6] = v;
    __syncthreads();
    if (threadIdx.x == 0) blocksum[blockIdx.x] = ws[0] + ws[1] + ws[2] + ws[3];
}

__global__ void scan_blocksums(int* __restrict__ blocksum, int nb) {
    __shared__ int buf[256];
    int t = threadIdx.x;
    int v = (t < nb) ? blocksum[t] : 0;
    buf[t] = v;
    __syncthreads();
    for (int off = 1; off < 256; off <<= 1) {
        int x = (t >= off) ? buf[t - off] : 0;
        __syncthreads();
        buf[t] += x;
        __syncthreads();
    }
    if (t < nb) blocksum[t] = buf[t] - v;  // exclusive
}

__global__ void scan_final(const int* __restrict__ deg, const int* __restrict__ blocksum,
                           int* __restrict__ rowptr, int* __restrict__ cursor, int N, int E) {
    int i = blockIdx.x * 256 + threadIdx.x;
    int lane = threadIdx.x & 63;
    int v = (i < N) ? deg[i] : 0;
    int x = v;
#pragma unroll
    for (int m = 1; m < 64; m <<= 1) {
        int y = __shfl_up(x, m, 64);
        if (lane >= m) x += y;
    }
    __shared__ int ws[4];
    if (lane == 63) ws[threadIdx.x >> 6] = x;
    __syncthreads();
    int w = threadIdx.x >> 6;
    int waveoff = 0;
#pragma unroll
    for (int k = 0; k < 4; k++) if (k < w) waveoff += ws[k];
    int excl = blocksum[blockIdx.x] + waveoff + x - v;
    if (i < N) { rowptr[i] = excl; cursor[i] = excl; }
    if (i == N - 1) rowptr[N] = E;
}

__global__ void scatter_edges(const int* __restrict__ src, const int* __restrict__ dst,
                              int* __restrict__ cursor, int2* __restrict__ cedge, int E) {
    int i = blockIdx.x * blockDim.x + threadIdx.x;
    if (i < E) {
        int d = dst[i];
        int pos = atomicAdd(&cursor[d], 1);
        cedge[pos] = make_int2(src[i], d);
    }
}

// ---------------- per-edge attention weights ----------------
__global__ void edge_w(const int2* __restrict__ cedge, const float* __restrict__ el,
                       const float* __restrict__ er, float2* __restrict__ ew, int E) {
    int i = blockIdx.x * blockDim.x + threadIdx.x;
    if (i >= E) return;
    int2 e = cedge[i];
    const float2* el2 = (const float2*)el;
    const float2* er2 = (const float2*)er;
    float2 l = el2[e.x], r = er2[e.y];
    float t0 = l.x + r.x; t0 = t0 > 0.f ? t0 : NEG_SLOPE * t0;
    float t1 = l.y + r.y; t1 = t1 > 0.f ? t1 : NEG_SLOPE * t1;
    ew[i] = make_float2(__expf(t0), __expf(t1));
}

// ---------------- GEMM + attention logits (W in VGPRs, no LDS) ----------------
template <int K>
__global__ __launch_bounds__(256, 2) void gemm32(
    const float* __restrict__ X, const float* __restrict__ W,
    const float* __restrict__ AL, const float* __restrict__ AR,
    __half* __restrict__ feat16, float* __restrict__ el, float* __restrict__ er, int N) {
    int wave = threadIdx.x >> 6, lane = threadIdx.x & 63;
    float w[K];
#pragma unroll
    for (int k = 0; k < K; k++) w[k] = W[k * 64 + lane];
    float alv = AL[lane], arv = AR[lane];
    for (int n0 = blockIdx.x * 4 + wave; n0 < N; n0 += gridDim.x * 4) {
        int n = rfl(n0);
        const float* __restrict__ xr = X + (size_t)n * K;
        float acc = 0.f;
#pragma unroll
        for (int k = 0; k < K; k++) acc = fmaf(xr[k], w[k], acc);
        feat16[(size_t)n * 64 + lane] = __float2half(acc);
        float vl = acc * alv, vr = acc * arv;
#pragma unroll
        for (int m = 1; m < 32; m <<= 1) {
            vl += __shfl_xor(vl, m, 64);
            vr += __shfl_xor(vr, m, 64);
        }
        if ((lane & 31) == 0) {
            int h = lane >> 5;
            el[n * 2 + h] = vl;
            er[n * 2 + h] = vr;
        }
    }
}

__global__ __launch_bounds__(256, 2) void gemm64(
    const float* __restrict__ X, const float* __restrict__ W,
    const float* __restrict__ AL, const float* __restrict__ AR,
    __half2* __restrict__ feat2, float* __restrict__ el, float* __restrict__ er, int N) {
    int wave = threadIdx.x >> 6, d = threadIdx.x & 63;
    float w0[64], w1[64];
#pragma unroll
    for (int k = 0; k < 64; k++) {
        w0[k] = W[k * 128 + d];
        w1[k] = W[k * 128 + 64 + d];
    }
    float al0 = AL[d], al1 = AL[64 + d], ar0 = AR[d], ar1 = AR[64 + d];
    for (int n0 = blockIdx.x * 4 + wave; n0 < N; n0 += gridDim.x * 4) {
        int n = rfl(n0);
        const float* __restrict__ xr = X + (size_t)n * 64;
        float a0 = 0.f, a1 = 0.f;
#pragma unroll
        for (int k = 0; k < 64; k++) {
            float xv = xr[k];
            a0 = fmaf(xv, w0[k], a0);
            a1 = fmaf(xv, w1[k], a1);
        }
        feat2[(size_t)n * 64 + d] = __floats2half2_rn(a0, a1);
        float l0 = a0 * al0, r0 = a0 * ar0;
        float l1 = a1 * al1, r1 = a1 * ar1;
#pragma unroll
        for (int m = 1; m < 64; m <<= 1) {
            l0 += __shfl_xor(l0, m, 64);
            r0 += __shfl_xor(r0, m, 64);
            l1 += __shfl_xor(l1, m, 64);
            r1 += __shfl_xor(r1, m, 64);
        }
        if (d == 0) {
            el[n * 2 + 0] = l0; el[n * 2 + 1] = l1;
            er[n * 2 + 0] = r0; er[n * 2 + 1] = r1;
        }
    }
}

// ---------------- Aggregation ----------------
// Layers 0/1: one wave per node, lane = h*32+d. Each lane shuffles BOTH head
// weights of edge j and selects by its OWN head after the broadcast (R3 bug fix).
template <bool RELU>
__global__ __launch_bounds__(256) void aggregate32(
    const int* __restrict__ rowptr, const int2* __restrict__ cedge,
    const float2* __restrict__ ew, const __half* __restrict__ feat16,
    const float* __restrict__ b, float* __restrict__ out, int N) {
    int wave = threadIdx.x >> 6, lane = threadIdx.x & 63, h = lane >> 5;
    int n = rfl(blockIdx.x * 4 + wave);
    if (n >= N) return;
    float bl = b[lane];
    int beg = rfl(rowptr[n]), end = rfl(rowptr[n + 1]);
    float s = 0.f, acc = 0.f;
    for (int base = beg; base < end; base += 64) {
        int idx = base + lane;
        int sv = 0; float wxv = 0.f, wyv = 0.f;
        if (idx < end) {
            sv = cedge[idx].x;
            float2 w2 = ew[idx];
            wxv = w2.x; wyv = w2.y;
        }
        int cnt = min(64, end - base);
        int j = 0;
        for (; j + 1 < cnt; j += 2) {
            int s0 = __shfl(sv, j, 64);
            int s1 = __shfl(sv, j + 1, 64);
            float wx0 = __shfl(wxv, j, 64), wy0 = __shfl(wyv, j, 64);
            float wx1 = __shfl(wxv, j + 1, 64), wy1 = __shfl(wyv, j + 1, 64);
            float w0 = h ? wy0 : wx0;
            float w1 = h ? wy1 : wx1;
            float f0 = __half2float(feat16[(size_t)s0 * 64 + lane]);
            float f1 = __half2float(feat16[(size_t)s1 * 64 + lane]);
            s += w0 + w1;
            acc = fmaf(w0, f0, acc);
            acc = fmaf(w1, f1, acc);
        }
        if (j < cnt) {
            int s0 = __shfl(sv, j, 64);
            float wx0 = __shfl(wxv, j, 64), wy0 = __shfl(wyv, j, 64);
            float w0 = h ? wy0 : wx0;
            float f0 = __half2float(feat16[(size_t)s0 * 64 + lane]);
            s += w0;
            acc = fmaf(w0, f0, acc);
        }
    }
    float v = (s > 0.f) ? acc / s : 0.f;
    v += bl;
    if (RELU) v = fmaxf(v, 0.f);
    out[(size_t)n * 64 + lane] = v;
}

// Layer 2: one wave per node, both heads via half2 interleave; mean over heads.
__global__ __launch_bounds__(256) void aggregate64_mean(
    const int* __restrict__ rowptr, const int2* __restrict__ cedge,
    const float2* __restrict__ ew, const __half2* __restrict__ feat2,
    const float* __restrict__ b, float* __restrict__ out, int N) {
    int wave = threadIdx.x >> 6, lane = threadIdx.x & 63;
    int n = rfl(blockIdx.x * 4 + wave);
    if (n >= N) return;
    float b0 = b[lane], b1 = b[64 + lane];
    int beg = rfl(rowptr[n]), end = rfl(rowptr[n + 1]);
    float s0 = 0.f, s1 = 0.f, a0 = 0.f, a1 = 0.f;
    for (int base = beg; base < end; base += 64) {
        int idx = base + lane;
        int sv = 0; float wx = 0.f, wy = 0.f;
        if (idx < end) {
            sv = cedge[idx].x;
            float2 w2 = ew[idx];
            wx = w2.x; wy = w2.y;
        }
        int cnt = min(64, end - base);
        for (int j = 0; j < cnt; j++) {
            int sj = __shfl(sv, j, 64);
            float w0 = __shfl(wx, j, 64);
            float w1 = __shfl(wy, j, 64);
            float2 ff = __half22float2(feat2[(size_t)sj * 64 + lane]);
            s0 += w0; s1 += w1;
            a0 = fmaf(w0, ff.x, a0);
            a1 = fmaf(w1, ff.y, a1);
        }
    }
    float v0 = (s0 > 0.f) ? a0 / s0 : 0.f;
    float v1 = (s1 > 0.f) ? a1 / s1 : 0.f;
    out[(size_t)n * 64 + lane] = 0.5f * ((v0 + b0) + (v1 + b1));
}

// ---------------- launcher ----------------

extern "C" void kernel_launch(void* const* d_in, const int* in_sizes, int n_in,
                              void* d_out, int out_size, void* d_ws, size_t ws_size,
                              hipStream_t stream) {
    const float* x   = (const float*)d_in[0];
    const int*   src = (const int*)d_in[1];
    const int*   dst = (const int*)d_in[2];
    const float* W0  = (const float*)d_in[3];
    const float* al0 = (const float*)d_in[4];
    const float* ar0 = (const float*)d_in[5];
    const float* b0  = (const float*)d_in[6];
    const float* W1  = (const float*)d_in[7];
    const float* al1 = (const float*)d_in[8];
    const float* ar1 = (const float*)d_in[9];
    const float* b1  = (const float*)d_in[10];
    const float* W2  = (const float*)d_in[11];
    const float* al2 = (const float*)d_in[12];
    const float* ar2 = (const float*)d_in[13];
    const float* b2  = (const float*)d_in[14];
    float* out = (float*)d_out;

    const int N = NNODES;
    const int E = in_sizes[1];

    char* p = (char*)d_ws;
    auto alloc = [&](size_t bytes) {
        void* r = (void*)p;
        p += (bytes + 255) & ~(size_t)255;
        return r;
    };
    int*    deg      = (int*)alloc((size_t)N * 4);
    int*    rowptr   = (int*)alloc((size_t)(N + 1) * 4);
    int*    cursor   = (int*)alloc((size_t)N * 4);
    int*    blocksum = (int*)alloc(256 * 4);
    int2*   cedge    = (int2*)alloc((size_t)E * 8);
    float2* ew       = (float2*)alloc((size_t)E * 8);
    float*  el       = (float*)alloc((size_t)N * 2 * 4);
    float*  er       = (float*)alloc((size_t)N * 2 * 4);
    void*   featbuf  = alloc((size_t)N * 64 * 4);
    float*  hbuf     = (float*)alloc((size_t)N * 64 * 4);
    __half*  feat16 = (__half*)featbuf;
    __half2* feat2  = (__half2*)featbuf;

    // CSR build (graph is layer-invariant)
    hipMemsetAsync(deg, 0, (size_t)N * 4, stream);
    int eb = (E + 255) / 256;
    int nb256 = (N + 255) / 256;
    count_deg<<<eb, 256, 0, stream>>>(dst, deg, E);
    scan_partial<<<nb256, 256, 0, stream>>>(deg, blocksum, N);
    scan_blocksums<<<1, 256, 0, stream>>>(blocksum, nb256);
    scan_final<<<nb256, 256, 0, stream>>>(deg, blocksum, rowptr, cursor, N, E);
    scatter_edges<<<eb, 256, 0, stream>>>(src, dst, cursor, cedge, E);

    int nb4 = (N + 3) / 4;        // one wave per node
    int gemmGrid = 768;           // grid-stride; W regs load once per block

    // layer 0: IN=128 -> H2xD32
    gemm32<128><<<gemmGrid, 256, 0, stream>>>(x, W0, al0, ar0, feat16, el, er, N);
    edge_w<<<eb, 256, 0, stream>>>(cedge, el, er, ew, E);
    aggregate32<true><<<nb4, 256, 0, stream>>>(rowptr, cedge, ew, feat16, b0, hbuf, N);

    // layer 1: 64 -> H2xD32
    gemm32<64><<<gemmGrid, 256, 0, stream>>>(hbuf, W1, al1, ar1, feat16, el, er, N);
    edge_w<<<eb, 256, 0, stream>>>(cedge, el, er, ew, E);
    aggregate32<true><<<nb4, 256, 0, stream>>>(rowptr, cedge, ew, feat16, b1, hbuf, N);

    // layer 2: 64 -> H2xD64, mean over heads
    gemm64<<<gemmGrid, 256, 0, stream>>>(hbuf, W2, al2, ar2, feat2, el, er, N);
    edge_w<<<eb, 256, 0, stream>>>(cedge, el, er, ew, E);
    aggregate64_mean<<<nb4, 256, 0, stream>>>(rowptr, cedge, ew, feat2, b2, out, N);
}

// Round 6
// 370.376 us; speedup vs baseline: 1.7199x; 1.0881x over previous
//
#include <hip/hip_runtime.h>
#include <hip/hip_bf16.h>
#include <hip/hip_fp16.h>

#define NNODES 50000
#define NEG_SLOPE 0.2f

__device__ __forceinline__ int rfl(int v) { return __builtin_amdgcn_readfirstlane(v); }

// ---------------- CSR build ----------------

__global__ void count_deg(const int* __restrict__ dst, int* __restrict__ deg, int E) {
    int i = blockIdx.x * blockDim.x + threadIdx.x;
    if (i < E) atomicAdd(&deg[dst[i]], 1);
}

__global__ void scan_partial(const int* __restrict__ deg, int* __restrict__ blocksum, int N) {
    int i = blockIdx.x * 256 + threadIdx.x;
    int v = (i < N) ? deg[i] : 0;
#pragma unroll
    for (int m = 1; m < 64; m <<= 1) v += __shfl_xor(v, m, 64);
    __shared__ int ws[4];
    if ((threadIdx.x & 63) == 0) ws[threadIdx.x >> 6] = v;
    __syncthreads();
    if (threadIdx.x == 0) blocksum[blockIdx.x] = ws[0] + ws[1] + ws[2] + ws[3];
}

__global__ void scan_blocksums(int* __restrict__ blocksum, int nb) {
    __shared__ int buf[256];
    int t = threadIdx.x;
    int v = (t < nb) ? blocksum[t] : 0;
    buf[t] = v;
    __syncthreads();
    for (int off = 1; off < 256; off <<= 1) {
        int x = (t >= off) ? buf[t - off] : 0;
        __syncthreads();
        buf[t] += x;
        __syncthreads();
    }
    if (t < nb) blocksum[t] = buf[t] - v;  // exclusive
}

__global__ void scan_final(const int* __restrict__ deg, const int* __restrict__ blocksum,
                           int* __restrict__ rowptr, int* __restrict__ cursor, int N, int E) {
    int i = blockIdx.x * 256 + threadIdx.x;
    int lane = threadIdx.x & 63;
    int v = (i < N) ? deg[i] : 0;
    int x = v;
#pragma unroll
    for (int m = 1; m < 64; m <<= 1) {
        int y = __shfl_up(x, m, 64);
        if (lane >= m) x += y;
    }
    __shared__ int ws[4];
    if (lane == 63) ws[threadIdx.x >> 6] = x;
    __syncthreads();
    int w = threadIdx.x >> 6;
    int waveoff = 0;
#pragma unroll
    for (int k = 0; k < 4; k++) if (k < w) waveoff += ws[k];
    int excl = blocksum[blockIdx.x] + waveoff + x - v;
    if (i < N) { rowptr[i] = excl; cursor[i] = excl; }
    if (i == N - 1) rowptr[N] = E;
}

__global__ void scatter_edges(const int* __restrict__ src, const int* __restrict__ dst,
                              int* __restrict__ cursor, int* __restrict__ csrc, int E) {
    int i = blockIdx.x * blockDim.x + threadIdx.x;
    if (i < E) {
        int pos = atomicAdd(&cursor[dst[i]], 1);
        csrc[pos] = src[i];
    }
}

// ---------------- GEMM + attention logits (W in VGPRs, float4 x loads) ----------------
template <int K>
__global__ __launch_bounds__(256, 2) void gemm32(
    const float* __restrict__ X, const float* __restrict__ W,
    const float* __restrict__ AL, const float* __restrict__ AR,
    __half* __restrict__ feat16, float* __restrict__ el, float* __restrict__ er, int N) {
    int wave = threadIdx.x >> 6, lane = threadIdx.x & 63;
    float w[K];
#pragma unroll
    for (int k = 0; k < K; k++) w[k] = W[k * 64 + lane];
    float alv = AL[lane], arv = AR[lane];
    for (int n0 = blockIdx.x * 4 + wave; n0 < N; n0 += gridDim.x * 4) {
        int n = rfl(n0);
        const float4* __restrict__ x4 = (const float4*)(X + (size_t)n * K);
        float acc = 0.f;
#pragma unroll
        for (int k4 = 0; k4 < K / 4; k4++) {
            float4 xv = x4[k4];
            acc = fmaf(xv.x, w[4 * k4 + 0], acc);
            acc = fmaf(xv.y, w[4 * k4 + 1], acc);
            acc = fmaf(xv.z, w[4 * k4 + 2], acc);
            acc = fmaf(xv.w, w[4 * k4 + 3], acc);
        }
        feat16[(size_t)n * 64 + lane] = __float2half(acc);
        float vl = acc * alv, vr = acc * arv;
#pragma unroll
        for (int m = 1; m < 32; m <<= 1) {
            vl += __shfl_xor(vl, m, 64);
            vr += __shfl_xor(vr, m, 64);
        }
        if ((lane & 31) == 0) {
            int h = lane >> 5;
            el[n * 2 + h] = vl;
            er[n * 2 + h] = vr;
        }
    }
}

__global__ __launch_bounds__(256, 2) void gemm64(
    const float* __restrict__ X, const float* __restrict__ W,
    const float* __restrict__ AL, const float* __restrict__ AR,
    __half2* __restrict__ feat2, float* __restrict__ el, float* __restrict__ er, int N) {
    int wave = threadIdx.x >> 6, d = threadIdx.x & 63;
    float w0[64], w1[64];
#pragma unroll
    for (int k = 0; k < 64; k++) {
        w0[k] = W[k * 128 + d];
        w1[k] = W[k * 128 + 64 + d];
    }
    float al0 = AL[d], al1 = AL[64 + d], ar0 = AR[d], ar1 = AR[64 + d];
    for (int n0 = blockIdx.x * 4 + wave; n0 < N; n0 += gridDim.x * 4) {
        int n = rfl(n0);
        const float4* __restrict__ x4 = (const float4*)(X + (size_t)n * 64);
        float a0 = 0.f, a1 = 0.f;
#pragma unroll
        for (int k4 = 0; k4 < 16; k4++) {
            float4 xv = x4[k4];
            a0 = fmaf(xv.x, w0[4 * k4 + 0], a0); a1 = fmaf(xv.x, w1[4 * k4 + 0], a1);
            a0 = fmaf(xv.y, w0[4 * k4 + 1], a0); a1 = fmaf(xv.y, w1[4 * k4 + 1], a1);
            a0 = fmaf(xv.z, w0[4 * k4 + 2], a0); a1 = fmaf(xv.z, w1[4 * k4 + 2], a1);
            a0 = fmaf(xv.w, w0[4 * k4 + 3], a0); a1 = fmaf(xv.w, w1[4 * k4 + 3], a1);
        }
        feat2[(size_t)n * 64 + d] = __floats2half2_rn(a0, a1);
        float l0 = a0 * al0, r0 = a0 * ar0;
        float l1 = a1 * al1, r1 = a1 * ar1;
#pragma unroll
        for (int m = 1; m < 64; m <<= 1) {
            l0 += __shfl_xor(l0, m, 64);
            r0 += __shfl_xor(r0, m, 64);
            l1 += __shfl_xor(l1, m, 64);
            r1 += __shfl_xor(r1, m, 64);
        }
        if (d == 0) {
            el[n * 2 + 0] = l0; el[n * 2 + 1] = l1;
            er[n * 2 + 0] = r0; er[n * 2 + 1] = r1;
        }
    }
}

// ---------------- Aggregation (fused edge weights, unroll x4) ----------------
// Layers 0/1: one wave per node, lane = h*32+d.
// NOTE: every __shfl must execute with FULL exec mask (ds_bpermute from an
// inactive lane is undefined) — shuffle both head weights unconditionally,
// select by the reader's h AFTER the broadcast. (R5 regression: ternary
// around the shfl diverged the wave.)
template <bool RELU>
__global__ __launch_bounds__(256) void aggregate32(
    const int* __restrict__ rowptr, const int* __restrict__ csrc,
    const float2* __restrict__ el2, const float2* __restrict__ er2,
    const __half* __restrict__ feat16, const float* __restrict__ b,
    float* __restrict__ out, int N) {
    int wave = threadIdx.x >> 6, lane = threadIdx.x & 63, h = lane >> 5;
    int n = rfl(blockIdx.x * 4 + wave);
    if (n >= N) return;
    float bl = b[lane];
    int beg = rfl(rowptr[n]), end = rfl(rowptr[n + 1]);
    float2 rr = er2[n];
    float s = 0.f, acc = 0.f;
    for (int base = beg; base < end; base += 64) {
        int idx = base + lane;
        int sv = 0; float wxv = 0.f, wyv = 0.f;
        if (idx < end) {
            sv = csrc[idx];
            float2 l = el2[sv];
            float t0 = l.x + rr.x; t0 = t0 > 0.f ? t0 : NEG_SLOPE * t0;
            float t1 = l.y + rr.y; t1 = t1 > 0.f ? t1 : NEG_SLOPE * t1;
            wxv = __expf(t0); wyv = __expf(t1);
        }
        int cnt = min(64, end - base);
        int j = 0;
        for (; j + 3 < cnt; j += 4) {
            int s0 = __shfl(sv, j, 64), s1 = __shfl(sv, j + 1, 64);
            int s2 = __shfl(sv, j + 2, 64), s3 = __shfl(sv, j + 3, 64);
            float wx0 = __shfl(wxv, j, 64),     wy0 = __shfl(wyv, j, 64);
            float wx1 = __shfl(wxv, j + 1, 64), wy1 = __shfl(wyv, j + 1, 64);
            float wx2 = __shfl(wxv, j + 2, 64), wy2 = __shfl(wyv, j + 2, 64);
            float wx3 = __shfl(wxv, j + 3, 64), wy3 = __shfl(wyv, j + 3, 64);
            float w0 = h ? wy0 : wx0;
            float w1 = h ? wy1 : wx1;
            float w2 = h ? wy2 : wx2;
            float w3 = h ? wy3 : wx3;
            float f0 = __half2float(feat16[(size_t)s0 * 64 + lane]);
            float f1 = __half2float(feat16[(size_t)s1 * 64 + lane]);
            float f2 = __half2float(feat16[(size_t)s2 * 64 + lane]);
            float f3 = __half2float(feat16[(size_t)s3 * 64 + lane]);
            s += (w0 + w1) + (w2 + w3);
            acc = fmaf(w0, f0, acc);
            acc = fmaf(w1, f1, acc);
            acc = fmaf(w2, f2, acc);
            acc = fmaf(w3, f3, acc);
        }
        for (; j < cnt; j++) {
            int s0 = __shfl(sv, j, 64);
            float wx0 = __shfl(wxv, j, 64), wy0 = __shfl(wyv, j, 64);
            float w0 = h ? wy0 : wx0;
            float f0 = __half2float(feat16[(size_t)s0 * 64 + lane]);
            s += w0;
            acc = fmaf(w0, f0, acc);
        }
    }
    float v = (s > 0.f) ? acc / s : 0.f;
    v += bl;
    if (RELU) v = fmaxf(v, 0.f);
    out[(size_t)n * 64 + lane] = v;
}

// Layer 2: one wave per node, both heads via half2 interleave; mean over heads.
__global__ __launch_bounds__(256) void aggregate64_mean(
    const int* __restrict__ rowptr, const int* __restrict__ csrc,
    const float2* __restrict__ el2, const float2* __restrict__ er2,
    const __half2* __restrict__ feat2, const float* __restrict__ b,
    float* __restrict__ out, int N) {
    int wave = threadIdx.x >> 6, lane = threadIdx.x & 63;
    int n = rfl(blockIdx.x * 4 + wave);
    if (n >= N) return;
    float b0 = b[lane], b1 = b[64 + lane];
    int beg = rfl(rowptr[n]), end = rfl(rowptr[n + 1]);
    float2 rr = er2[n];
    float s0 = 0.f, s1 = 0.f, a0 = 0.f, a1 = 0.f;
    for (int base = beg; base < end; base += 64) {
        int idx = base + lane;
        int sv = 0; float wxv = 0.f, wyv = 0.f;
        if (idx < end) {
            sv = csrc[idx];
            float2 l = el2[sv];
            float t0 = l.x + rr.x; t0 = t0 > 0.f ? t0 : NEG_SLOPE * t0;
            float t1 = l.y + rr.y; t1 = t1 > 0.f ? t1 : NEG_SLOPE * t1;
            wxv = __expf(t0); wyv = __expf(t1);
        }
        int cnt = min(64, end - base);
        int j = 0;
        for (; j + 3 < cnt; j += 4) {
            int e0 = __shfl(sv, j, 64), e1 = __shfl(sv, j + 1, 64);
            int e2 = __shfl(sv, j + 2, 64), e3 = __shfl(sv, j + 3, 64);
            float wx0 = __shfl(wxv, j, 64),     wy0 = __shfl(wyv, j, 64);
            float wx1 = __shfl(wxv, j + 1, 64), wy1 = __shfl(wyv, j + 1, 64);
            float wx2 = __shfl(wxv, j + 2, 64), wy2 = __shfl(wyv, j + 2, 64);
            float wx3 = __shfl(wxv, j + 3, 64), wy3 = __shfl(wyv, j + 3, 64);
            float2 f0 = __half22float2(feat2[(size_t)e0 * 64 + lane]);
            float2 f1 = __half22float2(feat2[(size_t)e1 * 64 + lane]);
            float2 f2 = __half22float2(feat2[(size_t)e2 * 64 + lane]);
            float2 f3 = __half22float2(feat2[(size_t)e3 * 64 + lane]);
            s0 += (wx0 + wx1) + (wx2 + wx3);
            s1 += (wy0 + wy1) + (wy2 + wy3);
            a0 = fmaf(wx0, f0.x, a0); a1 = fmaf(wy0, f0.y, a1);
            a0 = fmaf(wx1, f1.x, a0); a1 = fmaf(wy1, f1.y, a1);
            a0 = fmaf(wx2, f2.x, a0); a1 = fmaf(wy2, f2.y, a1);
            a0 = fmaf(wx3, f3.x, a0); a1 = fmaf(wy3, f3.y, a1);
        }
        for (; j < cnt; j++) {
            int e0 = __shfl(sv, j, 64);
            float wx0 = __shfl(wxv, j, 64), wy0 = __shfl(wyv, j, 64);
            float2 f0 = __half22float2(feat2[(size_t)e0 * 64 + lane]);
            s0 += wx0; s1 += wy0;
            a0 = fmaf(wx0, f0.x, a0); a1 = fmaf(wy0, f0.y, a1);
        }
    }
    float v0 = (s0 > 0.f) ? a0 / s0 : 0.f;
    float v1 = (s1 > 0.f) ? a1 / s1 : 0.f;
    out[(size_t)n * 64 + lane] = 0.5f * ((v0 + b0) + (v1 + b1));
}

// ---------------- launcher ----------------

extern "C" void kernel_launch(void* const* d_in, const int* in_sizes, int n_in,
                              void* d_out, int out_size, void* d_ws, size_t ws_size,
                              hipStream_t stream) {
    const float* x   = (const float*)d_in[0];
    const int*   src = (const int*)d_in[1];
    const int*   dst = (const int*)d_in[2];
    const float* W0  = (const float*)d_in[3];
    const float* al0 = (const float*)d_in[4];
    const float* ar0 = (const float*)d_in[5];
    const float* b0  = (const float*)d_in[6];
    const float* W1  = (const float*)d_in[7];
    const float* al1 = (const float*)d_in[8];
    const float* ar1 = (const float*)d_in[9];
    const float* b1  = (const float*)d_in[10];
    const float* W2  = (const float*)d_in[11];
    const float* al2 = (const float*)d_in[12];
    const float* ar2 = (const float*)d_in[13];
    const float* b2  = (const float*)d_in[14];
    float* out = (float*)d_out;

    const int N = NNODES;
    const int E = in_sizes[1];

    char* p = (char*)d_ws;
    auto alloc = [&](size_t bytes) {
        void* r = (void*)p;
        p += (bytes + 255) & ~(size_t)255;
        return r;
    };
    int*    deg      = (int*)alloc((size_t)N * 4);
    int*    rowptr   = (int*)alloc((size_t)(N + 1) * 4);
    int*    cursor   = (int*)alloc((size_t)N * 4);
    int*    blocksum = (int*)alloc(256 * 4);
    int*    csrc     = (int*)alloc((size_t)E * 4);
    float*  el       = (float*)alloc((size_t)N * 2 * 4);
    float*  er       = (float*)alloc((size_t)N * 2 * 4);
    void*   featbuf  = alloc((size_t)N * 64 * 4);
    float*  hbuf     = (float*)alloc((size_t)N * 64 * 4);
    __half*  feat16 = (__half*)featbuf;
    __half2* feat2  = (__half2*)featbuf;
    float2* el2 = (float2*)el;
    float2* er2 = (float2*)er;

    // CSR build (graph is layer-invariant)
    hipMemsetAsync(deg, 0, (size_t)N * 4, stream);
    int eb = (E + 255) / 256;
    int nb256 = (N + 255) / 256;
    count_deg<<<eb, 256, 0, stream>>>(dst, deg, E);
    scan_partial<<<nb256, 256, 0, stream>>>(deg, blocksum, N);
    scan_blocksums<<<1, 256, 0, stream>>>(blocksum, nb256);
    scan_final<<<nb256, 256, 0, stream>>>(deg, blocksum, rowptr, cursor, N, E);
    scatter_edges<<<eb, 256, 0, stream>>>(src, dst, cursor, csrc, E);

    int nb4 = (N + 3) / 4;        // one wave per node
    int gemmGrid = 2048;          // grid-stride

    // layer 0: IN=128 -> H2xD32
    gemm32<128><<<gemmGrid, 256, 0, stream>>>(x, W0, al0, ar0, feat16, el, er, N);
    aggregate32<true><<<nb4, 256, 0, stream>>>(rowptr, csrc, el2, er2, feat16, b0, hbuf, N);

    // layer 1: 64 -> H2xD32
    gemm32<64><<<gemmGrid, 256, 0, stream>>>(hbuf, W1, al1, ar1, feat16, el, er, N);
    aggregate32<true><<<nb4, 256, 0, stream>>>(rowptr, csrc, el2, er2, feat16, b1, hbuf, N);

    // layer 2: 64 -> H2xD64, mean over heads
    gemm64<<<gemmGrid, 256, 0, stream>>>(hbuf, W2, al2, ar2, feat2, el, er, N);
    aggregate64_mean<<<nb4, 256, 0, stream>>>(rowptr, csrc, el2, er2, feat2, b2, out, N);
}